// Round 10
// baseline (49.001 us; speedup 1.0000x reference)
//
#include <hip/hip_runtime.h>

#define N_INPUTS   1024
#define MAX_HIDDEN 2048
#define MAX_LAYERS 4
#define TOTAL_HIDDEN 8192
#define N_OUTPUTS  512
#define MAX_CONN   2048
#define MAX_OUT_CONN 4096
#define N_VALUES   9216

// Masked, bounds-checked 4-conn dot: ids >= bound refer to not-yet-computed
// layers whose value is semantically zero (no LDS zero-fill needed).
__device__ __forceinline__ float dot4b(int4 ia, float4 wa, int4 ma,
                                       const float* __restrict__ vals, int bound)
{
    float s = 0.f;
    s = fmaf((ma.x && ia.x < bound) ? vals[ia.x] : 0.f, wa.x, s);
    s = fmaf((ma.y && ia.y < bound) ? vals[ia.y] : 0.f, wa.y, s);
    s = fmaf((ma.z && ia.z < bound) ? vals[ia.z] : 0.f, wa.z, s);
    s = fmaf((ma.w && ia.w < bound) ? vals[ia.w] : 0.f, wa.w, s);
    return s;
}

__device__ __forceinline__ float dot4(int4 ia, float4 wa, int4 ma,
                                      const float* __restrict__ vals)
{
    float s = 0.f;
    s = fmaf(ma.x ? vals[ia.x] : 0.f, wa.x, s);
    s = fmaf(ma.y ? vals[ia.y] : 0.f, wa.y, s);
    s = fmaf(ma.z ? vals[ia.z] : 0.f, wa.z, s);
    s = fmaf(ma.w ? vals[ia.w] : 0.f, wa.w, s);
    return s;
}

// Hidden layer: 2048 neurons x 2048 conns. 512 blocks x 512 threads
// (4 blocks/CU). 4 neurons/block, 2 waves/neuron, 16 conns/lane as 4
// contiguous 4-conn groups. Stream loads issued in two batches of 6
// (before/after staging) to stay under the 64-VGPR cap.
__global__ void __launch_bounds__(512, 8)
hidden_layer_kernel(const float* __restrict__ g_in,
                    float* __restrict__ gvals,
                    const int* __restrict__ ids,
                    const float* __restrict__ wts,
                    const int* __restrict__ cmask,
                    const int* __restrict__ amask,
                    int row_base)
{
    __shared__ float vals[N_VALUES];
    __shared__ float psum[8];

    const int tid  = threadIdx.x;
    const int wave = tid >> 6;
    const int lane = tid & 63;

    const int neuron = (blockIdx.x << 2) + (wave >> 1);
    const size_t c0  = (size_t)(row_base + neuron) * MAX_CONN
                     + ((size_t)(wave & 1) << 10) + (lane << 2);

    // ---- batch 1: groups 0,1 in flight during LDS staging ----
    int4   ia0 = *reinterpret_cast<const int4*>(ids + c0);
    float4 wa0 = *reinterpret_cast<const float4*>(wts + c0);
    int4   ma0 = *reinterpret_cast<const int4*>(cmask + c0);
    int4   ia1 = *reinterpret_cast<const int4*>(ids + c0 + 256);
    float4 wa1 = *reinterpret_cast<const float4*>(wts + c0 + 256);
    int4   ma1 = *reinterpret_cast<const int4*>(cmask + c0 + 256);

    // ---- stage prefix only: inputs + already-computed layers ----
    const int bound = N_INPUTS + row_base;
    {
        const float4* in4 = reinterpret_cast<const float4*>(g_in);
        const float4* gv4 = reinterpret_cast<const float4*>(gvals);
        float4* s4 = reinterpret_cast<float4*>(vals);
        const int nin4 = N_INPUTS >> 2;
        const int pre4 = bound >> 2;
        for (int i = tid; i < pre4; i += 512)
            s4[i] = (i < nin4) ? in4[i] : gv4[i - nin4];
    }
    __syncthreads();

    // ---- batch 2: groups 2,3 in flight while computing groups 0,1 ----
    int4   ia2 = *reinterpret_cast<const int4*>(ids + c0 + 512);
    float4 wa2 = *reinterpret_cast<const float4*>(wts + c0 + 512);
    int4   ma2 = *reinterpret_cast<const int4*>(cmask + c0 + 512);
    int4   ia3 = *reinterpret_cast<const int4*>(ids + c0 + 768);
    float4 wa3 = *reinterpret_cast<const float4*>(wts + c0 + 768);
    int4   ma3 = *reinterpret_cast<const int4*>(cmask + c0 + 768);

    float sum = dot4b(ia0, wa0, ma0, vals, bound)
              + dot4b(ia1, wa1, ma1, vals, bound)
              + dot4b(ia2, wa2, ma2, vals, bound)
              + dot4b(ia3, wa3, ma3, vals, bound);

    #pragma unroll
    for (int off = 32; off > 0; off >>= 1)
        sum += __shfl_xor(sum, off, 64);

    if (lane == 0) psum[wave] = sum;
    __syncthreads();

    if (tid < 4) {
        const int n = (blockIdx.x << 2) + tid;
        float s = psum[tid << 1] + psum[(tid << 1) + 1];
        float a = tanhf(s);
        if (amask[row_base + n] == 0) a = 0.f;
        gvals[row_base + n] = a;
    }
}

// Output layer: 512 neurons x 4096 conns. 256 blocks x 512 threads.
// 2 neurons/block, 4 waves/neuron, 16 conns/lane as 4 contiguous groups.
__global__ void __launch_bounds__(512, 8)
output_layer_kernel(const float* __restrict__ g_in,
                    const float* __restrict__ gvals,
                    const int* __restrict__ ids,
                    const float* __restrict__ wts,
                    const int* __restrict__ cmask,
                    float* __restrict__ out)
{
    __shared__ float vals[N_VALUES];
    __shared__ float psum[8];

    const int tid  = threadIdx.x;
    const int wave = tid >> 6;
    const int lane = tid & 63;

    const int neuron = (blockIdx.x << 1) + (wave >> 2);
    const size_t c0  = (size_t)neuron * MAX_OUT_CONN
                     + ((size_t)(wave & 3) << 10) + (lane << 2);

    int4   ia0 = *reinterpret_cast<const int4*>(ids + c0);
    float4 wa0 = *reinterpret_cast<const float4*>(wts + c0);
    int4   ma0 = *reinterpret_cast<const int4*>(cmask + c0);
    int4   ia1 = *reinterpret_cast<const int4*>(ids + c0 + 256);
    float4 wa1 = *reinterpret_cast<const float4*>(wts + c0 + 256);
    int4   ma1 = *reinterpret_cast<const int4*>(cmask + c0 + 256);

    {
        const float4* in4 = reinterpret_cast<const float4*>(g_in);
        const float4* gv4 = reinterpret_cast<const float4*>(gvals);
        float4* s4 = reinterpret_cast<float4*>(vals);
        const int nin4 = N_INPUTS >> 2;
        for (int i = tid; i < (N_VALUES >> 2); i += 512)
            s4[i] = (i < nin4) ? in4[i] : gv4[i - nin4];
    }
    __syncthreads();

    int4   ia2 = *reinterpret_cast<const int4*>(ids + c0 + 512);
    float4 wa2 = *reinterpret_cast<const float4*>(wts + c0 + 512);
    int4   ma2 = *reinterpret_cast<const int4*>(cmask + c0 + 512);
    int4   ia3 = *reinterpret_cast<const int4*>(ids + c0 + 768);
    float4 wa3 = *reinterpret_cast<const float4*>(wts + c0 + 768);
    int4   ma3 = *reinterpret_cast<const int4*>(cmask + c0 + 768);

    float sum = dot4(ia0, wa0, ma0, vals)
              + dot4(ia1, wa1, ma1, vals)
              + dot4(ia2, wa2, ma2, vals)
              + dot4(ia3, wa3, ma3, vals);

    #pragma unroll
    for (int off = 32; off > 0; off >>= 1)
        sum += __shfl_xor(sum, off, 64);

    if (lane == 0) psum[wave] = sum;
    __syncthreads();

    if (tid < 2) {
        float s = psum[(tid << 2)] + psum[(tid << 2) + 1]
                + psum[(tid << 2) + 2] + psum[(tid << 2) + 3];
        out[(blockIdx.x << 1) + tid] = s;
    }
}

extern "C" void kernel_launch(void* const* d_in, const int* in_sizes, int n_in,
                              void* d_out, int out_size, void* d_ws, size_t ws_size,
                              hipStream_t stream) {
    const float* input_values = (const float*)d_in[0];
    const int*   h_ids        = (const int*)d_in[1];
    const float* h_w          = (const float*)d_in[2];
    const int*   h_cm         = (const int*)d_in[3];
    const int*   h_am         = (const int*)d_in[4];
    const int*   o_ids        = (const int*)d_in[5];
    const float* o_w          = (const float*)d_in[6];
    const int*   o_cm         = (const int*)d_in[7];
    float* out   = (float*)d_out;
    float* gvals = (float*)d_ws;   // hidden activations: 8192 floats

    for (int k = 0; k < MAX_LAYERS; ++k) {
        hidden_layer_kernel<<<512, 512, 0, stream>>>(
            input_values, gvals, h_ids, h_w, h_cm, h_am, k * MAX_HIDDEN);
    }

    output_layer_kernel<<<256, 512, 0, stream>>>(
        input_values, gvals, o_ids, o_w, o_cm, out);
}

// Round 11
// 48.223 us; speedup vs baseline: 1.0161x; 1.0161x over previous
//
#include <hip/hip_runtime.h>

#define N_INPUTS   1024
#define MAX_HIDDEN 2048
#define MAX_LAYERS 4
#define TOTAL_HIDDEN 8192
#define N_OUTPUTS  512
#define MAX_CONN   2048
#define MAX_OUT_CONN 4096
#define N_VALUES   9216

// Masked, bounds-checked 4-conn dot: ids >= bound refer to not-yet-computed
// layers whose value is semantically zero (no LDS zero-fill needed).
__device__ __forceinline__ float dot4b(int4 ia, float4 wa, int4 ma,
                                       const float* __restrict__ vals, int bound)
{
    float s = 0.f;
    s = fmaf((ma.x && ia.x < bound) ? vals[ia.x] : 0.f, wa.x, s);
    s = fmaf((ma.y && ia.y < bound) ? vals[ia.y] : 0.f, wa.y, s);
    s = fmaf((ma.z && ia.z < bound) ? vals[ia.z] : 0.f, wa.z, s);
    s = fmaf((ma.w && ia.w < bound) ? vals[ia.w] : 0.f, wa.w, s);
    return s;
}

__device__ __forceinline__ float dot4(int4 ia, float4 wa, int4 ma,
                                      const float* __restrict__ vals)
{
    float s = 0.f;
    s = fmaf(ma.x ? vals[ia.x] : 0.f, wa.x, s);
    s = fmaf(ma.y ? vals[ia.y] : 0.f, wa.y, s);
    s = fmaf(ma.z ? vals[ia.z] : 0.f, wa.z, s);
    s = fmaf(ma.w ? vals[ia.w] : 0.f, wa.w, s);
    return s;
}

// Hidden layer: 2048 neurons x 2048 conns. 1024 blocks x 512 threads
// (4 blocks/CU, 32 waves/CU). 2 neurons/block, 4 waves/neuron, 8 conns/lane
// as 2 contiguous 4-conn groups (each VMEM inst covers a contiguous 1KB).
// LDS staged with the [0, 1024+row_base) prefix ONLY; gathers bound-check.
__global__ void __launch_bounds__(512, 8)
hidden_layer_kernel(const float* __restrict__ g_in,
                    float* __restrict__ gvals,
                    const int* __restrict__ ids,
                    const float* __restrict__ wts,
                    const int* __restrict__ cmask,
                    const int* __restrict__ amask,
                    int row_base)
{
    __shared__ float vals[N_VALUES];
    __shared__ float psum[8];

    const int tid  = threadIdx.x;
    const int wave = tid >> 6;
    const int lane = tid & 63;

    const int neuron = (blockIdx.x << 1) + (wave >> 2);
    const int q      = wave & 3;
    const size_t c0  = (size_t)(row_base + neuron) * MAX_CONN + (q << 9) + (lane << 2);

    // ---- issue stream loads first (in flight during LDS staging) ----
    int4   ia0 = *reinterpret_cast<const int4*>(ids + c0);
    float4 wa0 = *reinterpret_cast<const float4*>(wts + c0);
    int4   ma0 = *reinterpret_cast<const int4*>(cmask + c0);
    int4   ia1 = *reinterpret_cast<const int4*>(ids + c0 + 256);
    float4 wa1 = *reinterpret_cast<const float4*>(wts + c0 + 256);
    int4   ma1 = *reinterpret_cast<const int4*>(cmask + c0 + 256);

    // ---- stage prefix only: inputs + already-computed layers ----
    const int bound = N_INPUTS + row_base;
    {
        const float4* in4 = reinterpret_cast<const float4*>(g_in);
        const float4* gv4 = reinterpret_cast<const float4*>(gvals);
        float4* s4 = reinterpret_cast<float4*>(vals);
        const int nin4 = N_INPUTS >> 2;
        const int pre4 = bound >> 2;
        for (int i = tid; i < pre4; i += 512)
            s4[i] = (i < nin4) ? in4[i] : gv4[i - nin4];
    }
    __syncthreads();

    float sum = dot4b(ia0, wa0, ma0, vals, bound)
              + dot4b(ia1, wa1, ma1, vals, bound);

    #pragma unroll
    for (int off = 32; off > 0; off >>= 1)
        sum += __shfl_xor(sum, off, 64);

    if (lane == 0) psum[wave] = sum;
    __syncthreads();

    if (tid < 2) {
        const int n = (blockIdx.x << 1) + tid;
        float s = psum[(tid << 2)] + psum[(tid << 2) + 1]
                + psum[(tid << 2) + 2] + psum[(tid << 2) + 3];
        float a = tanhf(s);
        if (amask[row_base + n] == 0) a = 0.f;
        gvals[row_base + n] = a;
    }
}

// Output layer: 512 neurons x 4096 conns. 512 blocks x 512 threads.
// 1 neuron/block, 8 waves, 8 conns/lane as 2 contiguous groups. Full staging.
__global__ void __launch_bounds__(512, 8)
output_layer_kernel(const float* __restrict__ g_in,
                    const float* __restrict__ gvals,
                    const int* __restrict__ ids,
                    const float* __restrict__ wts,
                    const int* __restrict__ cmask,
                    float* __restrict__ out)
{
    __shared__ float vals[N_VALUES];
    __shared__ float psum[8];

    const int tid  = threadIdx.x;
    const int wave = tid >> 6;
    const int lane = tid & 63;

    const size_t c0 = (size_t)blockIdx.x * MAX_OUT_CONN + (wave << 9) + (lane << 2);

    int4   ia0 = *reinterpret_cast<const int4*>(ids + c0);
    float4 wa0 = *reinterpret_cast<const float4*>(wts + c0);
    int4   ma0 = *reinterpret_cast<const int4*>(cmask + c0);
    int4   ia1 = *reinterpret_cast<const int4*>(ids + c0 + 256);
    float4 wa1 = *reinterpret_cast<const float4*>(wts + c0 + 256);
    int4   ma1 = *reinterpret_cast<const int4*>(cmask + c0 + 256);

    {
        const float4* in4 = reinterpret_cast<const float4*>(g_in);
        const float4* gv4 = reinterpret_cast<const float4*>(gvals);
        float4* s4 = reinterpret_cast<float4*>(vals);
        const int nin4 = N_INPUTS >> 2;
        for (int i = tid; i < (N_VALUES >> 2); i += 512)
            s4[i] = (i < nin4) ? in4[i] : gv4[i - nin4];
    }
    __syncthreads();

    float sum = dot4(ia0, wa0, ma0, vals) + dot4(ia1, wa1, ma1, vals);

    #pragma unroll
    for (int off = 32; off > 0; off >>= 1)
        sum += __shfl_xor(sum, off, 64);

    if (lane == 0) psum[wave] = sum;
    __syncthreads();

    if (tid == 0) {
        float s = 0.f;
        #pragma unroll
        for (int q = 0; q < 8; ++q) s += psum[q];
        out[blockIdx.x] = s;
    }
}

extern "C" void kernel_launch(void* const* d_in, const int* in_sizes, int n_in,
                              void* d_out, int out_size, void* d_ws, size_t ws_size,
                              hipStream_t stream) {
    const float* input_values = (const float*)d_in[0];
    const int*   h_ids        = (const int*)d_in[1];
    const float* h_w          = (const float*)d_in[2];
    const int*   h_cm         = (const int*)d_in[3];
    const int*   h_am         = (const int*)d_in[4];
    const int*   o_ids        = (const int*)d_in[5];
    const float* o_w          = (const float*)d_in[6];
    const int*   o_cm         = (const int*)d_in[7];
    float* out   = (float*)d_out;
    float* gvals = (float*)d_ws;   // hidden activations: 8192 floats

    for (int k = 0; k < MAX_LAYERS; ++k) {
        hidden_layer_kernel<<<1024, 512, 0, stream>>>(
            input_values, gvals, h_ids, h_w, h_cm, h_am, k * MAX_HIDDEN);
    }

    output_layer_kernel<<<512, 512, 0, stream>>>(
        input_values, gvals, o_ids, o_w, o_cm, out);
}